// Round 7
// baseline (249.548 us; speedup 1.0000x reference)
//
#include <hip/hip_runtime.h>
#include <hip/hip_fp16.h>

#define IMG_H 224
#define IMG_W 224
#define PLANE (IMG_H * IMG_W)    // 50176
#define NBLK  (256 * 7)          // 1792 band-blocks: image x 32-row band
#define TPB   128

typedef float fl4 __attribute__((ext_vector_type(4)));

// ws layout: [0,16) red u32[4] | [16,20) cnt u32 (monotonic, never reset)
//            [64, +NBLK*8) pr u64 | [+NBLK*8, +2*NBLK*8) pv u64
//            [32768, +25.7MB) rec fp16 planes | ves fp16 planes
#define WS_PR_OFF  64
#define WS_PLANES_OFF 32768
#define WS_NEED (WS_PLANES_OFF + 2ull * 256 * PLANE * 2)

// ---- ordered-uint mapping for float min/max ----
__device__ __forceinline__ unsigned int ford(float f) {
    unsigned int u = __float_as_uint(f);
    return (u & 0x80000000u) ? ~u : (u | 0x80000000u);
}
__device__ __forceinline__ float funord(unsigned int u) {
    unsigned int v = (u & 0x80000000u) ? (u & 0x7FFFFFFFu) : ~u;
    return __uint_as_float(v);
}

// Exact two-stage Sobel vesselness for border-ring pixels.
__device__ __forceinline__ float ves_exact(const float xs[36][44], int lr, int lc,
                                           int gr, int gc)
{
    float acc = 0.f;
    #pragma unroll
    for (int dr = -1; dr <= 1; ++dr) {
        #pragma unroll
        for (int dc = -1; dc <= 1; ++dc) {
            const int qr = gr + dr, qc = gc + dc;
            if ((unsigned)qr < IMG_H && (unsigned)qc < IMG_W) {
                const int a = lr + dr, b = lc + dc;
                const float gx = (xs[a-1][b+1] - xs[a-1][b-1])
                               + 2.f * (xs[a][b+1] - xs[a][b-1])
                               + (xs[a+1][b+1] - xs[a+1][b-1]);
                const float gy = (xs[a+1][b-1] - xs[a-1][b-1])
                               + 2.f * (xs[a+1][b] - xs[a-1][b])
                               + (xs[a+1][b+1] - xs[a-1][b+1]);
                const float kxw = (float)dc * ((dr == 0) ? 2.f : 1.f);
                const float kyw = (float)dr * ((dc == 0) ? 2.f : 1.f);
                acc += kxw * gx + kyw * gy;
            }
        }
    }
    return fabsf(acc);
}

struct TV { float xv[2][4], rec[2][4], ves[2][4]; };

__device__ __forceinline__ void stage_tile(const float* __restrict__ xp,
                                           float xs[36][44], int r0, int c0, int tid)
{
    #pragma unroll
    for (int k = 0; k < 3; ++k) {
        const int i = tid + k * TPB;
        if (i < 360) {
            const int r = i / 10, c4 = i - 10 * r;
            const int gr = r0 - 2 + r, gc = c0 - 4 + 4 * c4;
            fl4 v = (fl4)0.f;
            if ((unsigned)gr < IMG_H && (unsigned)gc < IMG_W)
                v = *(const fl4*)(xp + gr * IMG_W + gc);
            *(fl4*)&xs[r][4 * c4] = v;
        }
    }
}

// thread (tx,ty) owns 2 rows x 4 cols of the 32x32 tile (validated R3/R5/R6).
__device__ __forceinline__ void compute_tile(const float xs[36][44], int tx, int ty,
                                             int r0, int c0, TV& tv)
{
    float uu[6][4], ww[6][4];
    #pragma unroll
    for (int rr = 0; rr < 6; ++rr) {
        float ck[8];
        #pragma unroll
        for (int k = 0; k < 8; ++k) ck[k] = xs[2*ty + rr][4*tx + 2 + k];
        #pragma unroll
        for (int j = 0; j < 4; ++j) {
            uu[rr][j] = ck[j] - 2.f * ck[j+2] + ck[j+4];
            ww[rr][j] = ck[j] + 4.f * ck[j+1] + 6.f * ck[j+2] + 4.f * ck[j+3] + ck[j+4];
        }
    }
    #pragma unroll
    for (int s = 0; s < 2; ++s)
        #pragma unroll
        for (int j = 0; j < 4; ++j)
            tv.xv[s][j] = xs[2*ty + 2 + s][4*tx + 4 + j];

    #pragma unroll
    for (int q = 0; q < 2; ++q) {
        const float a = tv.xv[0][2*q], b = tv.xv[0][2*q+1];
        const float c = tv.xv[1][2*q], d = tv.xv[1][2*q+1];
        const float h0 = (a + b + c + d) * 0.5f;
        const float h1 = (a - b + c - d) * 0.5f;
        const float h2 = (a + b - c - d) * 0.5f;
        const float h3 = (a - b - c + d) * 0.5f;
        const float s0 = 0.1f*h0, s1 = 2.5f*h1, s2 = 2.5f*h2, s3 = 3.5f*h3;
        tv.rec[0][2*q]   = (s0 + s1 + s2 + s3) * 0.5f;
        tv.rec[0][2*q+1] = (s0 - s1 + s2 - s3) * 0.5f;
        tv.rec[1][2*q]   = (s0 + s1 - s2 - s3) * 0.5f;
        tv.rec[1][2*q+1] = (s0 - s1 - s2 + s3) * 0.5f;
    }

    #pragma unroll
    for (int s = 0; s < 2; ++s) {
        const int gr = r0 + 2*ty + s;
        const bool er = (gr == 0) | (gr == IMG_H - 1);
        #pragma unroll
        for (int j = 0; j < 4; ++j) {
            float t = uu[s][j] + 4.f*uu[s+1][j] + 6.f*uu[s+2][j] + 4.f*uu[s+3][j] + uu[s+4][j]
                    + ww[s][j] - 2.f*ww[s+2][j] + ww[s+4][j];
            float vv = fabsf(t);
            const int gc = c0 + 4*tx + j;
            if (er | (gc == 0) | (gc == IMG_W - 1))
                vv = ves_exact(xs, 2*ty + 2 + s, 4*tx + 4 + j, gr, gc);
            tv.ves[s][j] = vv;
        }
    }
}

// Pass 1: block = one 32-row band (7 tiles), register-prefetch double-buffered.
// Fused final reduction: last-arriving block reduces all partials -> red.
template<bool STORE>
__global__ __launch_bounds__(TPB)
void pass1_kernel(const float* __restrict__ x, float* __restrict__ out,
                  __half* __restrict__ recp, __half* __restrict__ vesp,
                  unsigned long long* __restrict__ pr,
                  unsigned long long* __restrict__ pv,
                  unsigned int* __restrict__ cnt,
                  unsigned int* __restrict__ red)
{
    __shared__ float xs[36][44];
    __shared__ unsigned int wred[2][4];
    __shared__ unsigned int lastflag;

    const int bid = blockIdx.x;
    const int tx = threadIdx.x, ty = threadIdx.y;
    const int tid = ty * 8 + tx;
    const int img = bid / 7;
    const int r0  = (bid % 7) * 32;
    const float* xp = x + (size_t)img * 3 * PLANE;

    stage_tile(xp, xs, r0, 0, tid);
    __syncthreads();

    float rmn = 3.4e38f, rmx = -3.4e38f, vmn = 3.4e38f, vmx = -3.4e38f;
    for (int t = 0; t < 7; ++t) {
        const int c0 = t * 32;

        // prefetch next tile into registers (latency hides under compute)
        fl4 pf[3];
        if (t < 6) {
            const int c0n = c0 + 32;
            #pragma unroll
            for (int k = 0; k < 3; ++k) {
                const int i = tid + k * TPB;
                pf[k] = (fl4)0.f;
                if (i < 360) {
                    const int r = i / 10, c4 = i - 10 * r;
                    const int gr = r0 - 2 + r, gc = c0n - 4 + 4 * c4;
                    if ((unsigned)gr < IMG_H && (unsigned)gc < IMG_W)
                        pf[k] = *(const fl4*)(xp + gr * IMG_W + gc);
                }
            }
        }

        TV tv;
        compute_tile(xs, tx, ty, r0, c0, tv);
        #pragma unroll
        for (int s = 0; s < 2; ++s)
            #pragma unroll
            for (int j = 0; j < 4; ++j) {
                rmn = fminf(rmn, tv.rec[s][j]); rmx = fmaxf(rmx, tv.rec[s][j]);
                vmn = fminf(vmn, tv.ves[s][j]); vmx = fmaxf(vmx, tv.ves[s][j]);
            }
        if constexpr (STORE) {
            const float m0 = 0.485f, i0 = 1.f / 0.229f;
            float* op = out + (size_t)img * 3 * PLANE
                            + (size_t)(r0 + 2*ty) * IMG_W + (c0 + 4*tx);
            const size_t poff = (size_t)img * PLANE
                              + (size_t)(r0 + 2*ty) * IMG_W + (c0 + 4*tx);
            #pragma unroll
            for (int s = 0; s < 2; ++s) {
                fl4 o0;
                #pragma unroll
                for (int j = 0; j < 4; ++j) o0[j] = (tv.xv[s][j] - m0) * i0;
                *(fl4*)(op + s * IMG_W) = o0;
                uint2 rr, vv;
                rr.x = __builtin_bit_cast(unsigned int, __floats2half2_rn(tv.rec[s][0], tv.rec[s][1]));
                rr.y = __builtin_bit_cast(unsigned int, __floats2half2_rn(tv.rec[s][2], tv.rec[s][3]));
                vv.x = __builtin_bit_cast(unsigned int, __floats2half2_rn(tv.ves[s][0], tv.ves[s][1]));
                vv.y = __builtin_bit_cast(unsigned int, __floats2half2_rn(tv.ves[s][2], tv.ves[s][3]));
                *(uint2*)(recp + poff + s * IMG_W) = rr;
                *(uint2*)(vesp + poff + s * IMG_W) = vv;
            }
        }
        __syncthreads();   // all reads of xs done
        if (t < 6) {
            #pragma unroll
            for (int k = 0; k < 3; ++k) {
                const int i = tid + k * TPB;
                if (i < 360) {
                    const int r = i / 10, c4 = i - 10 * r;
                    *(fl4*)&xs[r][4 * c4] = pf[k];
                }
            }
            __syncthreads();   // xs ready for next tile
        }
    }

    // block min/max -> partials
    #pragma unroll
    for (int off = 32; off; off >>= 1) {
        rmn = fminf(rmn, __shfl_down(rmn, off));
        rmx = fmaxf(rmx, __shfl_down(rmx, off));
        vmn = fminf(vmn, __shfl_down(vmn, off));
        vmx = fmaxf(vmx, __shfl_down(vmx, off));
    }
    if ((tid & 63) == 0) {
        const int w = tid >> 6;
        wred[w][0] = ford(rmn); wred[w][1] = ford(rmx);
        wred[w][2] = ford(vmn); wred[w][3] = ford(vmx);
    }
    __syncthreads();
    if (tid == 0) {
        const unsigned long long a = (unsigned long long)min(wred[0][0], wred[1][0])
                                   | ((unsigned long long)max(wred[0][1], wred[1][1]) << 32);
        const unsigned long long b = (unsigned long long)min(wred[0][2], wred[1][2])
                                   | ((unsigned long long)max(wred[0][3], wred[1][3]) << 32);
        __hip_atomic_store(&pr[bid], a, __ATOMIC_RELEASE, __HIP_MEMORY_SCOPE_AGENT);
        __hip_atomic_store(&pv[bid], b, __ATOMIC_RELEASE, __HIP_MEMORY_SCOPE_AGENT);
        const unsigned int old = __hip_atomic_fetch_add(cnt, 1u, __ATOMIC_ACQ_REL,
                                                        __HIP_MEMORY_SCOPE_AGENT);
        lastflag = ((old + 1u) % (unsigned)NBLK == 0u);  // monotonic: poison-proof
    }
    __syncthreads();

    // last-arriving block reduces all 1792 partials -> red[0..3]
    if (lastflag) {
        unsigned int mn0 = 0xFFFFFFFFu, mx1 = 0u, mn2 = 0xFFFFFFFFu, mx3 = 0u;
        for (int i = tid; i < NBLK; i += TPB) {
            const unsigned long long a = __hip_atomic_load(&pr[i], __ATOMIC_ACQUIRE,
                                                           __HIP_MEMORY_SCOPE_AGENT);
            const unsigned long long b = __hip_atomic_load(&pv[i], __ATOMIC_ACQUIRE,
                                                           __HIP_MEMORY_SCOPE_AGENT);
            mn0 = min(mn0, (unsigned int)a); mx1 = max(mx1, (unsigned int)(a >> 32));
            mn2 = min(mn2, (unsigned int)b); mx3 = max(mx3, (unsigned int)(b >> 32));
        }
        #pragma unroll
        for (int off = 32; off; off >>= 1) {
            mn0 = min(mn0, (unsigned int)__shfl_down((int)mn0, off));
            mx1 = max(mx1, (unsigned int)__shfl_down((int)mx1, off));
            mn2 = min(mn2, (unsigned int)__shfl_down((int)mn2, off));
            mx3 = max(mx3, (unsigned int)__shfl_down((int)mx3, off));
        }
        if ((tid & 63) == 0) {
            const int w = tid >> 6;
            wred[w][0] = mn0; wred[w][1] = mx1; wred[w][2] = mn2; wred[w][3] = mx3;
        }
        __syncthreads();
        if (tid == 0) {
            red[0] = min(wred[0][0], wred[1][0]);
            red[1] = max(wred[0][1], wred[1][1]);
            red[2] = min(wred[0][2], wred[1][2]);
            red[3] = max(wred[0][3], wred[1][3]);
        }
    }
}

// Fast pass 2: elementwise affine, 32 px/thread. 256*PLANE/32/TPB = 3136 blocks.
__global__ __launch_bounds__(TPB)
void pass2_affine(const __half* __restrict__ recp, const __half* __restrict__ vesp,
                  float* __restrict__ out, const unsigned int* __restrict__ red)
{
    const int gid = blockIdx.x * TPB + threadIdx.x;
    const int p   = gid * 32;
    const int img = p / PLANE;          // 32 | PLANE -> no straddling
    const int off = p - img * PLANE;

    const float rmin = funord(red[0]), rmax = funord(red[1]);
    const float vmin = funord(red[2]), vmax = funord(red[3]);
    const float rsc = 1.f / (rmax - rmin + 1e-6f);
    const float vsc = 1.f / (vmax - vmin + 1e-6f);
    const float m1 = 0.456f, i1 = 1.f / 0.224f;
    const float m2 = 0.406f, i2 = 1.f / 0.225f;

    const size_t pbase = (size_t)img * PLANE + off;
    uint4 rv[4], vv[4];
    const uint4* rp = (const uint4*)(recp + pbase);
    const uint4* vp = (const uint4*)(vesp + pbase);
    #pragma unroll
    for (int i = 0; i < 4; ++i) { rv[i] = rp[i]; vv[i] = vp[i]; }

    float* o1 = out + (size_t)img * 3 * PLANE + PLANE + off;
    float* o2 = o1 + PLANE;
    #pragma unroll
    for (int i = 0; i < 4; ++i) {
        const __half2* hr = (const __half2*)&rv[i];
        const __half2* hv = (const __half2*)&vv[i];
        fl4 a0, a1, b0, b1;
        #pragma unroll
        for (int j = 0; j < 2; ++j) {
            float2 r = __half22float2(hr[j]);
            float2 v = __half22float2(hv[j]);
            a0[2*j]   = ((r.x - rmin) * rsc - m1) * i1;
            a0[2*j+1] = ((r.y - rmin) * rsc - m1) * i1;
            b0[2*j]   = ((v.x - vmin) * vsc - m2) * i2;
            b0[2*j+1] = ((v.y - vmin) * vsc - m2) * i2;
        }
        #pragma unroll
        for (int j = 0; j < 2; ++j) {
            float2 r = __half22float2(hr[2 + j]);
            float2 v = __half22float2(hv[2 + j]);
            a1[2*j]   = ((r.x - rmin) * rsc - m1) * i1;
            a1[2*j+1] = ((r.y - rmin) * rsc - m1) * i1;
            b1[2*j]   = ((v.x - vmin) * vsc - m2) * i2;
            b1[2*j+1] = ((v.y - vmin) * vsc - m2) * i2;
        }
        *(fl4*)(o1 + i * 8)     = a0;
        *(fl4*)(o1 + i * 8 + 4) = a1;
        *(fl4*)(o2 + i * 8)     = b0;
        *(fl4*)(o2 + i * 8 + 4) = b1;
    }
}

// Fallback pass 2 (recompute all 3 channels) — only if ws is too small.
__global__ __launch_bounds__(TPB)
void pass2_full(const float* __restrict__ x, float* __restrict__ out,
                const unsigned int* __restrict__ red)
{
    __shared__ float xs[36][44];

    const int bid = blockIdx.x;
    const int tx = threadIdx.x, ty = threadIdx.y;
    const int tid = ty * 8 + tx;
    const int img = bid / 7;
    const int r0  = (bid % 7) * 32;
    const float* xp = x + (size_t)img * 3 * PLANE;

    const float rmin = funord(red[0]), rmax = funord(red[1]);
    const float vmin = funord(red[2]), vmax = funord(red[3]);
    const float rsc = 1.f / (rmax - rmin + 1e-6f);
    const float vsc = 1.f / (vmax - vmin + 1e-6f);
    const float m0 = 0.485f, i0 = 1.f / 0.229f;
    const float m1 = 0.456f, i1 = 1.f / 0.224f;
    const float m2 = 0.406f, i2 = 1.f / 0.225f;

    for (int t = 0; t < 7; ++t) {
        const int c0 = t * 32;
        stage_tile(xp, xs, r0, c0, tid);
        __syncthreads();
        TV tv;
        compute_tile(xs, tx, ty, r0, c0, tv);

        float* op = out + (size_t)img * 3 * PLANE
                        + (size_t)(r0 + 2*ty) * IMG_W + (c0 + 4*tx);
        #pragma unroll
        for (int s = 0; s < 2; ++s) {
            fl4 o0, o1, o2;
            #pragma unroll
            for (int j = 0; j < 4; ++j) {
                o0[j] = (tv.xv[s][j] - m0) * i0;
                o1[j] = ((tv.rec[s][j] - rmin) * rsc - m1) * i1;
                o2[j] = ((tv.ves[s][j] - vmin) * vsc - m2) * i2;
            }
            *(fl4*)(op + s * IMG_W) = o0;
            *(fl4*)(op + s * IMG_W + PLANE) = o1;
            *(fl4*)(op + s * IMG_W + 2 * PLANE) = o2;
        }
        __syncthreads();
    }
}

extern "C" void kernel_launch(void* const* d_in, const int* in_sizes, int n_in,
                              void* d_out, int out_size, void* d_ws, size_t ws_size,
                              hipStream_t stream) {
    const float* x = (const float*)d_in[0];
    float* out = (float*)d_out;
    unsigned int* red = (unsigned int*)d_ws;
    unsigned int* cnt = (unsigned int*)((char*)d_ws + 16);
    unsigned long long* pr = (unsigned long long*)((char*)d_ws + WS_PR_OFF);
    unsigned long long* pv = pr + NBLK;
    __half* recp = (__half*)((char*)d_ws + WS_PLANES_OFF);
    __half* vesp = recp + (size_t)256 * PLANE;

    dim3 block(8, 16);
    if (ws_size >= WS_NEED) {
        pass1_kernel<true><<<dim3(NBLK), block, 0, stream>>>(x, out, recp, vesp, pr, pv, cnt, red);
        pass2_affine<<<dim3(3136), TPB, 0, stream>>>(recp, vesp, out, red);
    } else {
        pass1_kernel<false><<<dim3(NBLK), block, 0, stream>>>(x, out, recp, vesp, pr, pv, cnt, red);
        pass2_full<<<dim3(NBLK), block, 0, stream>>>(x, out, red);
    }
}

// Round 8
// 61.342 us; speedup vs baseline: 4.0681x; 4.0681x over previous
//
#include <hip/hip_runtime.h>

#define IMG 224
#define PLANE (IMG * IMG)        // 50176
#define BANDROWS 14
#define NBANDS 16                // 16 * 14 = 224
#define NWAVES (256 * NBANDS)    // 4096 waves
#define NPBLK (NWAVES / 4)       // 1024 blocks of 4 waves

typedef float fl4 __attribute__((ext_vector_type(4)));

// ---- ordered-uint mapping for float min/max ----
__device__ __forceinline__ unsigned int ford(float f) {
    unsigned int u = __float_as_uint(f);
    return (u & 0x80000000u) ? ~u : (u | 0x80000000u);
}
__device__ __forceinline__ float funord(unsigned int u) {
    unsigned int v = (u & 0x80000000u) ? (u & 0x7FFFFFFFu) : ~u;
    return __uint_as_float(v);
}

// One wave = one 14-row band of one image. Lane L owns cols 4L..4L+3 (L<56).
// No LDS in the hot loop, no barriers, horizontal halo via __shfl, vertical
// window via register rings. Border-exactness via closed-form corrections
// (verified: exact = composed - [uu-ww]_edge_row - 4*(A[-1]+2A[0]+A[1])_edge_col
//  - 2*x at corners).
template<bool WRITE>
__global__ __launch_bounds__(256)
void band_kernel(const float* __restrict__ x, float* __restrict__ out,
                 uint4* __restrict__ partials, const unsigned int* __restrict__ red)
{
    const int wid  = (blockIdx.x << 2) + (threadIdx.x >> 6);
    const int lane = threadIdx.x & 63;
    const int img  = wid >> 4;
    const int band = wid & 15;
    const int r0   = band * BANDROWS;
    const bool active = lane < 56;
    const int col = lane * 4;
    const float* xp = x + (size_t)img * 3 * PLANE;

    float rmin = 0.f, rsc = 0.f, vmin = 0.f, vsc = 0.f;
    if constexpr (WRITE) {
        rmin = funord(red[0]); const float rmax = funord(red[1]);
        vmin = funord(red[2]); const float vmax = funord(red[3]);
        rsc = 1.f / (rmax - rmin + 1e-6f);
        vsc = 1.f / (vmax - vmin + 1e-6f);
    }
    const float m0 = 0.485f, i0 = 1.f / 0.229f;
    const float m1 = 0.456f, i1 = 1.f / 0.224f;
    const float m2 = 0.406f, i2 = 1.f / 0.225f;

    float rmn = 3.4e38f, rmx = -3.4e38f, vmn = 3.4e38f, vmx = -3.4e38f;

    auto loadrow = [&](int gr) -> fl4 {
        fl4 v = (fl4)0.f;
        if (active && (unsigned)gr < (unsigned)IMG)
            v = *(const fl4*)(xp + gr * IMG + col);
        return v;
    };

    // horizontal prefilters: uu = [1,0,-2,0,1]*x, ww = [1,4,6,4,1]*x (zero-pad)
    auto pref = [&](fl4 p, fl4& uu, fl4& ww) {
        float cl1 = __shfl_up(p[3], 1);
        float cl2 = __shfl_up(p[2], 1);
        float cr1 = __shfl_down(p[0], 1);   // lane56 p==0 -> right pad free
        float cr2 = __shfl_down(p[1], 1);
        if (lane == 0) { cl1 = 0.f; cl2 = 0.f; }
        uu[0] = cl2 - 2.f*p[0] + p[2];
        uu[1] = cl1 - 2.f*p[1] + p[3];
        uu[2] = p[0] - 2.f*p[2] + cr1;
        uu[3] = p[1] - 2.f*p[3] + cr2;
        ww[0] = cl2 + 4.f*cl1 + 6.f*p[0] + 4.f*p[1] + p[2];
        ww[1] = cl1 + 4.f*p[0] + 6.f*p[1] + 4.f*p[2] + p[3];
        ww[2] = p[0] + 4.f*p[1] + 6.f*p[2] + 4.f*p[3] + cr1;
        ww[3] = p[1] + 4.f*p[2] + 6.f*p[3] + 4.f*cr1 + cr2;
    };

    // Haar fwd+gain+inv for the row pair (xe=even row, xo=odd row)
    auto haar2 = [&](fl4 xe, fl4 xo, fl4& re_, fl4& ro_) {
        #pragma unroll
        for (int q = 0; q < 2; ++q) {
            const float a = xe[2*q], b = xe[2*q+1], c = xo[2*q], d = xo[2*q+1];
            const float h0 = (a+b+c+d)*0.5f, h1 = (a-b+c-d)*0.5f;
            const float h2 = (a+b-c-d)*0.5f, h3 = (a-b-c+d)*0.5f;
            const float s0 = 0.1f*h0, s1 = 2.5f*h1, s2 = 2.5f*h2, s3 = 3.5f*h3;
            re_[2*q]   = (s0+s1+s2+s3)*0.5f;
            re_[2*q+1] = (s0-s1+s2-s3)*0.5f;
            ro_[2*q]   = (s0+s1-s2-s3)*0.5f;
            ro_[2*q+1] = (s0-s1-s2+s3)*0.5f;
        }
    };

    // emit one output row: uu/ww rings a..e = rows gr-2..gr+2; pm1/p0c/pp1 =
    // x rows gr-1,gr,gr+1; recv = rec values for this row.
    auto dorow = [&](int gr, fl4 ua, fl4 ub, fl4 uc, fl4 ud, fl4 ue,
                     fl4 wa, fl4 wb, fl4 wc, fl4 wd, fl4 we,
                     fl4 pm1, fl4 p0c, fl4 pp1, fl4 recv) {
        fl4 t;
        #pragma unroll
        for (int j = 0; j < 4; ++j)
            t[j] = ua[j] + 4.f*ub[j] + 6.f*uc[j] + 4.f*ud[j] + ue[j]
                 + wa[j] - 2.f*wc[j] + we[j];
        const bool rb = (gr == 0) | (gr == IMG - 1);
        if (rb) {
            #pragma unroll
            for (int j = 0; j < 4; ++j) t[j] -= (uc[j] - wc[j]);
        }
        const float corr0 = -4.f*(pm1[0] + 2.f*p0c[0] + pp1[0]);
        const float corr3 = -4.f*(pm1[3] + 2.f*p0c[3] + pp1[3]);
        if (lane == 0)  t[0] -= corr0 + (rb ? 2.f*p0c[0] : 0.f);
        if (lane == 55) t[3] -= corr3 + (rb ? 2.f*p0c[3] : 0.f);
        fl4 ves;
        #pragma unroll
        for (int j = 0; j < 4; ++j) ves[j] = fabsf(t[j]);

        if (active) {
            #pragma unroll
            for (int j = 0; j < 4; ++j) {
                rmn = fminf(rmn, recv[j]); rmx = fmaxf(rmx, recv[j]);
                vmn = fminf(vmn, ves[j]);  vmx = fmaxf(vmx, ves[j]);
            }
            if constexpr (WRITE) {
                float* op = out + (size_t)img * 3 * PLANE + gr * IMG + col;
                fl4 o0, o1, o2;
                #pragma unroll
                for (int j = 0; j < 4; ++j) {
                    o0[j] = (p0c[j] - m0) * i0;
                    o1[j] = ((recv[j] - rmin) * rsc - m1) * i1;
                    o2[j] = ((ves[j]  - vmin) * vsc - m2) * i2;
                }
                *(fl4*)op               = o0;
                *(fl4*)(op + PLANE)     = o1;
                *(fl4*)(op + 2 * PLANE) = o2;
            }
        }
    };

    // ---- warm-up: rows r0-2 .. r0+1 ----
    fl4 uA, uB, uC, uD, wA, wB, wC, wD, pB, pC, pD;
    {
        fl4 pA = loadrow(r0 - 2); pref(pA, uA, wA);
        pB = loadrow(r0 - 1); pref(pB, uB, wB);
        pC = loadrow(r0);     pref(pC, uC, wC);
        pD = loadrow(r0 + 1); pref(pD, uD, wD);
    }

    // ---- march 7 row-pairs ----
    for (int k = 0; k < 7; ++k) {
        const int re = r0 + 2 * k;
        fl4 pE = loadrow(re + 2); fl4 uE, wE; pref(pE, uE, wE);
        fl4 rec_e, rec_o; haar2(pC, pD, rec_e, rec_o);
        dorow(re,     uA, uB, uC, uD, uE, wA, wB, wC, wD, wE, pB, pC, pD, rec_e);
        fl4 pF = loadrow(re + 3); fl4 uF, wF; pref(pF, uF, wF);
        dorow(re + 1, uB, uC, uD, uE, uF, wB, wC, wD, wE, wF, pC, pD, pE, rec_o);
        uA = uC; uB = uD; uC = uE; uD = uF;
        wA = wC; wB = wD; wC = wE; wD = wF;
        pB = pD; pC = pE; pD = pF;
    }

    if constexpr (!WRITE) {
        // inactive lanes kept init values (neutral). 64-lane shfl reduce.
        #pragma unroll
        for (int off = 32; off; off >>= 1) {
            rmn = fminf(rmn, __shfl_down(rmn, off));
            rmx = fmaxf(rmx, __shfl_down(rmx, off));
            vmn = fminf(vmn, __shfl_down(vmn, off));
            vmx = fmaxf(vmx, __shfl_down(vmx, off));
        }
        __shared__ uint4 wred[4];
        if (lane == 0) {
            uint4 p;
            p.x = ford(rmn); p.y = ford(rmx); p.z = ford(vmn); p.w = ford(vmx);
            wred[threadIdx.x >> 6] = p;
        }
        __syncthreads();
        if (threadIdx.x == 0) {
            uint4 p = wred[0];
            #pragma unroll
            for (int w = 1; w < 4; ++w) {
                p.x = min(p.x, wred[w].x); p.y = max(p.y, wred[w].y);
                p.z = min(p.z, wred[w].z); p.w = max(p.w, wred[w].w);
            }
            partials[blockIdx.x] = p;
        }
    }
}

// Reduce NPBLK uint4 partials -> red[0..3]. One 256-thread block, 16 KB read.
__global__ __launch_bounds__(256)
void reduce_partials(const uint4* __restrict__ partials, unsigned int* __restrict__ red)
{
    __shared__ unsigned int wred[4][4];
    const int tid = threadIdx.x;
    unsigned int mn0 = 0xFFFFFFFFu, mx1 = 0u, mn2 = 0xFFFFFFFFu, mx3 = 0u;
    for (int i = tid; i < NPBLK; i += 256) {
        uint4 p = partials[i];
        mn0 = min(mn0, p.x); mx1 = max(mx1, p.y);
        mn2 = min(mn2, p.z); mx3 = max(mx3, p.w);
    }
    #pragma unroll
    for (int off = 32; off; off >>= 1) {
        mn0 = min(mn0, (unsigned)__shfl_down((int)mn0, off));
        mx1 = max(mx1, (unsigned)__shfl_down((int)mx1, off));
        mn2 = min(mn2, (unsigned)__shfl_down((int)mn2, off));
        mx3 = max(mx3, (unsigned)__shfl_down((int)mx3, off));
    }
    const int wave = tid >> 6;
    if ((tid & 63) == 0) {
        wred[wave][0] = mn0; wred[wave][1] = mx1;
        wred[wave][2] = mn2; wred[wave][3] = mx3;
    }
    __syncthreads();
    if (tid == 0) {
        unsigned int a0 = wred[0][0], a1 = wred[0][1], a2 = wred[0][2], a3 = wred[0][3];
        #pragma unroll
        for (int w = 1; w < 4; ++w) {
            a0 = min(a0, wred[w][0]); a1 = max(a1, wred[w][1]);
            a2 = min(a2, wred[w][2]); a3 = max(a3, wred[w][3]);
        }
        red[0] = a0; red[1] = a1; red[2] = a2; red[3] = a3;
    }
}

extern "C" void kernel_launch(void* const* d_in, const int* in_sizes, int n_in,
                              void* d_out, int out_size, void* d_ws, size_t ws_size,
                              hipStream_t stream) {
    const float* x = (const float*)d_in[0];
    float* out = (float*)d_out;
    unsigned int* red = (unsigned int*)d_ws;           // 4 uints
    uint4* partials = (uint4*)((char*)d_ws + 64);      // NPBLK uint4 = 16 KB

    band_kernel<false><<<dim3(NPBLK), 256, 0, stream>>>(x, nullptr, partials, nullptr);
    reduce_partials<<<1, 256, 0, stream>>>(partials, red);
    band_kernel<true ><<<dim3(NPBLK), 256, 0, stream>>>(x, out, nullptr, red);
}